// Round 4
// baseline (693.441 us; speedup 1.0000x reference)
//
#include <hip/hip_runtime.h>
#include <hip/hip_bf16.h>
#include <stdint.h>

typedef __bf16 bf16;
typedef __bf16 bf16x8 __attribute__((ext_vector_type(8)));
typedef float f32x4 __attribute__((ext_vector_type(4)));
typedef unsigned short u16;

constexpr int NB = 4;
constexpr int NT = 2048;
constexpr int NC = 2048;
constexpr int NH = 16;
constexpr int ND = 128;
constexpr int NC3 = 6144;

__device__ __forceinline__ void gload16(const void* g, void* l) {
  __builtin_amdgcn_global_load_lds((const __attribute__((address_space(1))) void*)g,
                                   (__attribute__((address_space(3))) void*)l, 16, 0, 0);
}

// ---------------- input dtype probe: flag[0]=1 if x is f32, 0 if bf16 ----------------
// bf16 N(0,1) data: both u16 halves have bf16-exponent in [0x70,0x85] ~always.
// f32 N(0,1) data: only the high half does (~54% combined).
__global__ void dtype_detect_k(const unsigned int* x, int* flag) {
  __shared__ int cnt;
  if (threadIdx.x == 0) cnt = 0;
  __syncthreads();
  int c = 0;
  for (int i = threadIdx.x; i < 4096; i += 256) {
    unsigned v = x[i];
    unsigned e0 = (v >> 7) & 0xffu, e1 = (v >> 23) & 0xffu;
    c += (e0 >= 0x70u && e0 <= 0x85u) + (e1 >= 0x70u && e1 <= 0x85u);
  }
  atomicAdd(&cnt, c);
  __syncthreads();
  if (threadIdx.x == 0) flag[0] = (cnt < 7373) ? 1 : 0;   // <90% of 8192 -> f32
}

// ---------------- ingest: raw (bf16 or f32 per flag) -> bf16, n multiple of 8 ----------------
__global__ __launch_bounds__(256) void ingest_k(const void* raw, bf16* out, long n, const int* flag) {
  long i = ((long)blockIdx.x * 256 + threadIdx.x) * 8;
  if (i >= n) return;
  if (flag[0]) {
    const float* f = (const float*)raw;
    f32x4 a = *(const f32x4*)(f + i), b = *(const f32x4*)(f + i + 4);
    bf16x8 o;
    o[0] = (bf16)a[0]; o[1] = (bf16)a[1]; o[2] = (bf16)a[2]; o[3] = (bf16)a[3];
    o[4] = (bf16)b[0]; o[5] = (bf16)b[1]; o[6] = (bf16)b[2]; o[7] = (bf16)b[3];
    *(bf16x8*)(out + i) = o;
  } else {
    *(bf16x8*)(out + i) = *(const bf16x8*)((const bf16*)raw + i);
  }
}

// ---------------- mask format detect + expand to int32 ----------------
__global__ void mask_prep_k(const void* raw, int* out) {
  __shared__ int s_gt1, s_oddnz, s_allb, s_allf, s_allh;
  if (threadIdx.x == 0) { s_gt1 = 0; s_oddnz = 0; s_allb = 1; s_allf = 1; s_allh = 1; }
  __syncthreads();
  const unsigned int* mw = (const unsigned int*)raw;
  int gt1 = 0, oddnz = 0, allb = 1, allf = 1, allh = 1;
  for (int i = threadIdx.x; i < 2048; i += 256) {   // first 8KB: safe for every candidate layout
    unsigned v = mw[i];
    if (v > 1u) gt1 = 1;
    if ((i & 1) && v) oddnz = 1;
#pragma unroll
    for (int bb = 0; bb < 4; ++bb) { unsigned by = (v >> (8*bb)) & 0xffu; if (by > 1u) allb = 0; }
    if (v != 0u && v != 0x3F800000u) allf = 0;
    unsigned lo = v & 0xffffu, hi = v >> 16;
    if ((lo != 0u && lo != 0x3F80u) || (hi != 0u && hi != 0x3F80u)) allh = 0;
  }
  if (gt1) atomicOr(&s_gt1, 1);
  if (oddnz) atomicOr(&s_oddnz, 1);
  if (!allb) atomicAnd(&s_allb, 0);
  if (!allf) atomicAnd(&s_allf, 0);
  if (!allh) atomicAnd(&s_allh, 0);
  __syncthreads();
  int mode;
  if (!s_gt1)       mode = s_oddnz ? 0 : 2;  // int32 : int64
  else if (s_allf)  mode = 3;                // f32 0/1
  else if (s_allb)  mode = 1;                // packed bytes (bool)
  else if (s_allh)  mode = 4;                // bf16/f16 halves
  else              mode = 0;                // fallback int32
  for (int i = threadIdx.x; i < NB*NT; i += 256) {
    int v;
    if (mode == 0)      v = (((const int*)raw)[i] != 0);
    else if (mode == 1) v = (((const unsigned char*)raw)[i] != 0);
    else if (mode == 2) v = (((const long long*)raw)[i] != 0);
    else if (mode == 3) v = (((const unsigned int*)raw)[i] != 0);
    else                v = (((const unsigned short*)raw)[i] != 0);
    out[i] = v;
  }
}

// ---------------- generic bf16 transpose: out[c][r] = in[r][c], 64x64 tiles ----------------
__global__ __launch_bounds__(256) void transpose_k(const bf16* __restrict__ in, bf16* __restrict__ out,
                                                   int in_rs, int out_rs) {
  __shared__ __align__(16) bf16 t[64][72];
  const int r0 = blockIdx.y << 6, c0 = blockIdx.x << 6;
  const int tid = threadIdx.x;
#pragma unroll
  for (int i = 0; i < 2; ++i) {
    int slot = i*256 + tid, row = slot >> 3, c8 = slot & 7;
    bf16x8 v = *(const bf16x8*)(in + (long)(r0 + row)*in_rs + c0 + c8*8);
#pragma unroll
    for (int e = 0; e < 8; ++e) t[c8*8 + e][row] = v[e];
  }
  __syncthreads();
#pragma unroll
  for (int i = 0; i < 2; ++i) {
    int slot = i*256 + tid, row = slot >> 3, c8 = slot & 7;
    bf16x8 v = *(const bf16x8*)(&t[row][c8*8]);
    *(bf16x8*)(out + (long)(c0 + row)*out_rs + r0 + c8*8) = v;
  }
}

// ---------------- V^T extraction: vt[(b*H+h)*128 + d][t] = qkv[b*T+t][4096 + h*128 + d] ----------------
__global__ __launch_bounds__(256) void vtrans_k(const bf16* __restrict__ qkv, bf16* __restrict__ vt) {
  __shared__ __align__(16) bf16 t[64][72];
  const int tt = blockIdx.x, dh = blockIdx.y, bh = blockIdx.z;
  const int b = bh >> 4, h = bh & 15;
  const int tid = threadIdx.x;
  const bf16* src = qkv + (long)(b*NT + tt*64)*NC3 + (2*NC + h*ND + dh*64);
#pragma unroll
  for (int i = 0; i < 2; ++i) {
    int slot = i*256 + tid, row = slot >> 3, c8 = slot & 7;
    bf16x8 v = *(const bf16x8*)(src + (long)row*NC3 + c8*8);
#pragma unroll
    for (int e = 0; e < 8; ++e) t[c8*8 + e][row] = v[e];
  }
  __syncthreads();
  bf16* dst = vt + ((long)bh*ND + dh*64)*NT + tt*64;
#pragma unroll
  for (int i = 0; i < 2; ++i) {
    int slot = i*256 + tid, row = slot >> 3, c8 = slot & 7;
    bf16x8 v = *(const bf16x8*)(&t[row][c8*8]);
    *(bf16x8*)(dst + (long)row*NT + c8*8) = v;
  }
}

// ---------------- GEMM: C[M,N] = A[M,K] * B, with BT = B^T [N,K] row-major ----------------
// 128x128 tile, BK=64, 4 waves (64x64 each), swizzled LDS, global_load_lds x16B.
// OT = bf16 (intermediates) or float (final output buffer is f32).
template <typename OT>
__global__ __launch_bounds__(256, 2) void gemm_bt_k(const bf16* __restrict__ A, const bf16* __restrict__ BT,
                                                    OT* __restrict__ Cout, int M, int N, int K) {
  const int tid = threadIdx.x, w = tid >> 6, l = tid & 63, g = l >> 4, r = l & 15;
  const int wr = w >> 1, wc = w & 1;
  const long m0 = (long)blockIdx.y << 7, n0 = (long)blockIdx.x << 7;
  __shared__ __align__(16) char As[16384];
  __shared__ __align__(16) char Bs[16384];

  long aoff[4], boff[4];
  char *al_[4], *bl_[4];
#pragma unroll
  for (int i = 0; i < 4; ++i) {
    int slot = i*256 + tid, row = slot >> 3, c = slot & 7, cp = c ^ (row & 7);
    aoff[i] = (m0 + row)*(long)K + cp*8;
    boff[i] = (n0 + row)*(long)K + cp*8;
    al_[i] = As + ((i*256 + w*64) << 4);
    bl_[i] = Bs + ((i*256 + w*64) << 4);
  }

  const f32x4 z4 = {0.f, 0.f, 0.f, 0.f};
  f32x4 acc[4][4];
#pragma unroll
  for (int mc = 0; mc < 4; ++mc)
#pragma unroll
    for (int nc = 0; nc < 4; ++nc) acc[mc][nc] = z4;

  for (int k0 = 0; k0 < K; k0 += 64) {
#pragma unroll
    for (int i = 0; i < 4; ++i) {
      gload16(A + aoff[i] + k0, al_[i]);
      gload16(BT + boff[i] + k0, bl_[i]);
    }
    __syncthreads();
#pragma unroll
    for (int kk = 0; kk < 2; ++kk) {
      bf16x8 af[4], bfr[4];
#pragma unroll
      for (int mc = 0; mc < 4; ++mc) {
        int row = wr*64 + mc*16 + r;
        af[mc] = *(const bf16x8*)(As + row*128 + (((kk*4 + g) ^ (row & 7)) << 4));
      }
#pragma unroll
      for (int nc = 0; nc < 4; ++nc) {
        int row = wc*64 + nc*16 + r;
        bfr[nc] = *(const bf16x8*)(Bs + row*128 + (((kk*4 + g) ^ (row & 7)) << 4));
      }
#pragma unroll
      for (int mc = 0; mc < 4; ++mc)
#pragma unroll
        for (int nc = 0; nc < 4; ++nc)
          acc[mc][nc] = __builtin_amdgcn_mfma_f32_16x16x32_bf16(af[mc], bfr[nc], acc[mc][nc], 0, 0, 0);
    }
    __syncthreads();
  }
#pragma unroll
  for (int mc = 0; mc < 4; ++mc)
#pragma unroll
    for (int nc = 0; nc < 4; ++nc)
#pragma unroll
      for (int j = 0; j < 4; ++j) {
        long mr = m0 + wr*64 + mc*16 + 4*g + j;
        long nc_ = n0 + wc*64 + nc*16 + r;
        Cout[mr*(long)N + nc_] = (OT)acc[mc][nc][j];
      }
}

// ---------------- fused causal+masked flash attention ----------------
// block = (qt, h, b): 64 q-rows, 4 waves x 16 rows. K tile [64][128] + V^T tile [128][64] in LDS.
__global__ __launch_bounds__(256, 2) void attn_k(const bf16* __restrict__ qkv, const bf16* __restrict__ vt,
                                                 const int* __restrict__ mask, bf16* __restrict__ y) {
  const int qt = blockIdx.x, h = blockIdx.y, b = blockIdx.z;
  const int tid = threadIdx.x, w = tid >> 6, l = tid & 63, g = l >> 4, r = l & 15;
  const int q0 = qt << 6;
  const int bh = b*NH + h;

  __shared__ __align__(16) char Klds[16384];   // [64 key][128 d], swizzled 16B slots
  __shared__ __align__(16) char Vlds[16384];   // [128 d][64 key], swizzled
  __shared__ __align__(16) char Plds[8192];    // per-wave [16 q][64 key] bf16, swizzled
  char* Pl = Plds + (w << 11);

  long koff[4], voff[4];
  char *kl_[4], *vl_[4];
#pragma unroll
  for (int i = 0; i < 4; ++i) {
    int slot = i*256 + tid;                    // K: 64 rows x 16 slots
    int row = slot >> 4, c = slot & 15, cp = c ^ (row & 7);
    koff[i] = (long)row*NC3 + cp*8;
    kl_[i] = Klds + ((i*256 + w*64) << 4);
    int vrow = slot >> 3, vc = slot & 7, vcp = vc ^ (vrow & 7);   // VT: 128 rows x 8 slots
    voff[i] = (long)vrow*NT + vcp*8;
    vl_[i] = Vlds + ((i*256 + w*64) << 4);
  }
  const bf16* kbase0 = qkv + (long)(b*NT)*NC3 + (NC + h*ND);
  const bf16* vbase0 = vt + (long)bh*ND*NT;

  bf16x8 qf[4];
  {
    const int qrow = q0 + w*16 + r;
    const bf16* qp = qkv + (long)(b*NT + qrow)*NC3 + h*ND + g*8;
#pragma unroll
    for (int dk = 0; dk < 4; ++dk) qf[dk] = *(const bf16x8*)(qp + dk*32);
  }

  const f32x4 z4 = {0.f, 0.f, 0.f, 0.f};
  f32x4 acc[8];
#pragma unroll
  for (int i = 0; i < 8; ++i) acc[i] = z4;
  float m_run[4], l_run[4];
#pragma unroll
  for (int j = 0; j < 4; ++j) { m_run[j] = -3.0e38f; l_run[j] = 0.f; }

  const float SCL = 0.08838834764831845f * 1.4426950408889634f;  // 1/sqrt(128) * log2(e)

  for (int kt = 0; kt <= qt; ++kt) {
    const bf16* kb = kbase0 + (long)(kt*64)*NC3;
    const bf16* vb = vbase0 + kt*64;
#pragma unroll
    for (int i = 0; i < 4; ++i) {
      gload16(kb + koff[i], kl_[i]);
      gload16(vb + voff[i], vl_[i]);
    }
    __syncthreads();

    int mv[4];
#pragma unroll
    for (int kc = 0; kc < 4; ++kc) mv[kc] = mask[b*NT + kt*64 + kc*16 + r];
    const int diag = (kt == qt);

    float tv[4][4];
    float tmax[4] = {-3.0e38f, -3.0e38f, -3.0e38f, -3.0e38f};
#pragma unroll
    for (int kc = 0; kc < 4; ++kc) {
      f32x4 s = z4;
      const int krow = kc*16 + r;
#pragma unroll
      for (int dk = 0; dk < 4; ++dk) {
        bf16x8 kf = *(const bf16x8*)(Klds + krow*256 + (((dk*4 + g) ^ (krow & 7)) << 4));
        s = __builtin_amdgcn_mfma_f32_16x16x32_bf16(qf[dk], kf, s, 0, 0, 0);
      }
      const int key = kt*64 + kc*16 + r;
#pragma unroll
      for (int j = 0; j < 4; ++j) {
        int qrow = q0 + w*16 + 4*g + j;
        float sv = (mv[kc] && (!diag || key <= qrow)) ? s[j]*SCL : -3.0e38f;
        tv[kc][j] = sv;
        tmax[j] = fmaxf(tmax[j], sv);
      }
    }
#pragma unroll
    for (int j = 0; j < 4; ++j) {
#pragma unroll
      for (int off = 1; off < 16; off <<= 1) tmax[j] = fmaxf(tmax[j], __shfl_xor(tmax[j], off));
    }
    float al[4], rs[4];
#pragma unroll
    for (int j = 0; j < 4; ++j) {
      float mn = fmaxf(m_run[j], tmax[j]);
      al[j] = exp2f(m_run[j] - mn);
      m_run[j] = mn;
      rs[j] = 0.f;
    }
#pragma unroll
    for (int kc = 0; kc < 4; ++kc) {
#pragma unroll
      for (int j = 0; j < 4; ++j) {
        float p = exp2f(tv[kc][j] - m_run[j]);
        rs[j] += p;
        int prow = 4*g + j;
        int cb = (kc*16 + r)*2;
        int sl = (cb >> 4) ^ (prow & 7);
        *(u16*)(Pl + prow*128 + (sl << 4) + (cb & 15)) = __builtin_bit_cast(u16, (bf16)p);
      }
    }
#pragma unroll
    for (int j = 0; j < 4; ++j) {
#pragma unroll
      for (int off = 1; off < 16; off <<= 1) rs[j] += __shfl_xor(rs[j], off);
      l_run[j] = l_run[j]*al[j] + rs[j];
    }
#pragma unroll
    for (int d0 = 0; d0 < 8; ++d0) {
#pragma unroll
      for (int j = 0; j < 4; ++j) acc[d0][j] *= al[j];
    }
    // P writes (same-wave DS, in-order) must be visible before P reads: fence both
    // the hardware counter and the scheduler (rule #18).
    asm volatile("s_waitcnt lgkmcnt(0)" ::: "memory");
    __builtin_amdgcn_sched_barrier(0);
    bf16x8 pa[2];
#pragma unroll
    for (int kk = 0; kk < 2; ++kk)
      pa[kk] = *(const bf16x8*)(Pl + r*128 + (((kk*4 + g) ^ (r & 7)) << 4));
#pragma unroll
    for (int d0 = 0; d0 < 8; ++d0) {
      const int vrow = d0*16 + r;
#pragma unroll
      for (int kk = 0; kk < 2; ++kk) {
        bf16x8 vf = *(const bf16x8*)(Vlds + vrow*128 + (((kk*4 + g) ^ (vrow & 7)) << 4));
        acc[d0] = __builtin_amdgcn_mfma_f32_16x16x32_bf16(pa[kk], vf, acc[d0], 0, 0, 0);
      }
    }
    __syncthreads();
  }

  float inv[4];
#pragma unroll
  for (int j = 0; j < 4; ++j) inv[j] = 1.0f / l_run[j];
#pragma unroll
  for (int d0 = 0; d0 < 8; ++d0) {
#pragma unroll
    for (int j = 0; j < 4; ++j) {
      int qrow = q0 + w*16 + 4*g + j;
      y[(long)(b*NT + qrow)*NC + h*ND + d0*16 + r] = (bf16)(acc[d0][j]*inv[j]);
    }
  }
}

extern "C" void kernel_launch(void* const* d_in, const int* in_sizes, int n_in,
                              void* d_out, int out_size, void* d_ws, size_t ws_size,
                              hipStream_t stream) {
  const void* xr    = d_in[0];
  const void* tok   = d_in[1];
  const void* wqkvr = d_in[2];
  const void* wprojr= d_in[3];
  float* out = (float*)d_out;                       // reference output dtype is f32
  char* ws = (char*)d_ws;

  bf16* qkv    = (bf16*)(ws);                       // 100,663,296 B
  bf16* yattn  = (bf16*)(ws + 100663296L);          //  33,554,432 B
  bf16* wT     = (bf16*)(ws + 134217728L);          //  25,165,824 B (transposed W, reused)
  bf16* wb     = (bf16*)(ws + 159383552L);          //  25,165,824 B (bf16 ingest of W, reused)
  bf16* xb     = (bf16*)(ws + 184549376L);          //  33,554,432 B (bf16 x; reused as vtb)
  bf16* vtb    = xb;                                //  alias: xb dead after GEMM1
  int*  flag   = (int*)(ws + 218103808L);           //         128 B
  int*  maskI  = (int*)(ws + 218103936L);           //      32,768 B  (total ~208 MiB)

  dtype_detect_k<<<1, 256, 0, stream>>>((const unsigned int*)xr, flag);
  mask_prep_k<<<1, 256, 0, stream>>>(tok, maskI);
  // ingest x and W_qkv to bf16
  ingest_k<<<8192, 256, 0, stream>>>(xr, xb, 16777216L, flag);
  ingest_k<<<6144, 256, 0, stream>>>(wqkvr, wb, 12582912L, flag);
  // W_qkv^T [6144][2048]
  transpose_k<<<dim3(96, 32), 256, 0, stream>>>(wb, wT, NC3, NC);
  // qkv = x @ W_qkv
  gemm_bt_k<bf16><<<dim3(48, 64), 256, 0, stream>>>(xb, wT, qkv, 8192, 6144, 2048);
  // V^T per (b,h)  (vtb aliases xb — xb dead after GEMM1)
  vtrans_k<<<dim3(32, 2, 64), 256, 0, stream>>>(qkv, vtb);
  // W_proj ingest + transpose (reuses wb/wT regions)
  ingest_k<<<2048, 256, 0, stream>>>(wprojr, wb, 4194304L, flag);
  transpose_k<<<dim3(32, 32), 256, 0, stream>>>(wb, wT, NC, NC);
  // attention
  attn_k<<<dim3(32, 16, 4), 256, 0, stream>>>(qkv, vtb, maskI, yattn);
  // out = y @ W_proj  (f32 output)
  gemm_bt_k<float><<<dim3(16, 64), 256, 0, stream>>>(yattn, wT, out, 8192, 2048, 2048);
}

// Round 6
// 662.718 us; speedup vs baseline: 1.0464x; 1.0464x over previous
//
#include <hip/hip_runtime.h>
#include <hip/hip_bf16.h>
#include <stdint.h>

typedef __bf16 bf16;
typedef __bf16 bf16x8 __attribute__((ext_vector_type(8)));
typedef float f32x4 __attribute__((ext_vector_type(4)));
typedef unsigned short u16;

constexpr int NB = 4;
constexpr int NT = 2048;
constexpr int NC = 2048;
constexpr int NH = 16;
constexpr int ND = 128;
constexpr int NC3 = 6144;

#define SWZP(row) ((((row) >> 2) << 1) | ((row) & 1))

__device__ __forceinline__ void gload16(const void* g, void* l) {
  __builtin_amdgcn_global_load_lds((const __attribute__((address_space(1))) void*)g,
                                   (__attribute__((address_space(3))) void*)l, 16, 0, 0);
}

// ---------------- ingest: f32 -> bf16, n multiple of 8 ----------------
__global__ __launch_bounds__(256) void ingest_k(const float* __restrict__ raw, bf16* __restrict__ out, long n) {
  long i = ((long)blockIdx.x * 256 + threadIdx.x) * 8;
  if (i >= n) return;
  f32x4 a = *(const f32x4*)(raw + i), b = *(const f32x4*)(raw + i + 4);
  bf16x8 o;
  o[0] = (bf16)a[0]; o[1] = (bf16)a[1]; o[2] = (bf16)a[2]; o[3] = (bf16)a[3];
  o[4] = (bf16)b[0]; o[5] = (bf16)b[1]; o[6] = (bf16)b[2]; o[7] = (bf16)b[3];
  *(bf16x8*)(out + i) = o;
}

// ---------------- mask format detect + expand to int32 (proven round 4) ----------------
__global__ void mask_prep_k(const void* raw, int* out) {
  __shared__ int s_gt1, s_oddnz, s_allb, s_allf, s_allh;
  if (threadIdx.x == 0) { s_gt1 = 0; s_oddnz = 0; s_allb = 1; s_allf = 1; s_allh = 1; }
  __syncthreads();
  const unsigned int* mw = (const unsigned int*)raw;
  int gt1 = 0, oddnz = 0, allb = 1, allf = 1, allh = 1;
  for (int i = threadIdx.x; i < 2048; i += 256) {
    unsigned v = mw[i];
    if (v > 1u) gt1 = 1;
    if ((i & 1) && v) oddnz = 1;
#pragma unroll
    for (int bb = 0; bb < 4; ++bb) { unsigned by = (v >> (8*bb)) & 0xffu; if (by > 1u) allb = 0; }
    if (v != 0u && v != 0x3F800000u) allf = 0;
    unsigned lo = v & 0xffffu, hi = v >> 16;
    if ((lo != 0u && lo != 0x3F80u) || (hi != 0u && hi != 0x3F80u)) allh = 0;
  }
  if (gt1) atomicOr(&s_gt1, 1);
  if (oddnz) atomicOr(&s_oddnz, 1);
  if (!allb) atomicAnd(&s_allb, 0);
  if (!allf) atomicAnd(&s_allf, 0);
  if (!allh) atomicAnd(&s_allh, 0);
  __syncthreads();
  int mode;
  if (!s_gt1)       mode = s_oddnz ? 0 : 2;
  else if (s_allf)  mode = 3;
  else if (s_allb)  mode = 1;
  else if (s_allh)  mode = 4;
  else              mode = 0;
  for (int i = threadIdx.x; i < NB*NT; i += 256) {
    int v;
    if (mode == 0)      v = (((const int*)raw)[i] != 0);
    else if (mode == 1) v = (((const unsigned char*)raw)[i] != 0);
    else if (mode == 2) v = (((const long long*)raw)[i] != 0);
    else if (mode == 3) v = (((const unsigned int*)raw)[i] != 0);
    else                v = (((const unsigned short*)raw)[i] != 0);
    out[i] = v;
  }
}

// ---------------- generic bf16 transpose: out[c][r] = in[r][c], 64x64 tiles ----------------
__global__ __launch_bounds__(256) void transpose_k(const bf16* __restrict__ in, bf16* __restrict__ out,
                                                   int in_rs, int out_rs) {
  __shared__ __align__(16) bf16 t[64][72];
  const int r0 = blockIdx.y << 6, c0 = blockIdx.x << 6;
  const int tid = threadIdx.x;
#pragma unroll
  for (int i = 0; i < 2; ++i) {
    int slot = i*256 + tid, row = slot >> 3, c8 = slot & 7;
    bf16x8 v = *(const bf16x8*)(in + (long)(r0 + row)*in_rs + c0 + c8*8);
#pragma unroll
    for (int e = 0; e < 8; ++e) t[c8*8 + e][row] = v[e];
  }
  __syncthreads();
#pragma unroll
  for (int i = 0; i < 2; ++i) {
    int slot = i*256 + tid, row = slot >> 3, c8 = slot & 7;
    bf16x8 v = *(const bf16x8*)(&t[row][c8*8]);
    *(bf16x8*)(out + (long)(c0 + row)*out_rs + r0 + c8*8) = v;
  }
}

// ---------------- V^T extraction: vt[(b*H+h)*128 + d][t] = qkv[b*T+t][4096 + h*128 + d] ----------------
__global__ __launch_bounds__(256) void vtrans_k(const bf16* __restrict__ qkv, bf16* __restrict__ vt) {
  __shared__ __align__(16) bf16 t[64][72];
  const int tt = blockIdx.x, dh = blockIdx.y, bh = blockIdx.z;
  const int b = bh >> 4, h = bh & 15;
  const int tid = threadIdx.x;
  const bf16* src = qkv + (long)(b*NT + tt*64)*NC3 + (2*NC + h*ND + dh*64);
#pragma unroll
  for (int i = 0; i < 2; ++i) {
    int slot = i*256 + tid, row = slot >> 3, c8 = slot & 7;
    bf16x8 v = *(const bf16x8*)(src + (long)row*NC3 + c8*8);
#pragma unroll
    for (int e = 0; e < 8; ++e) t[c8*8 + e][row] = v[e];
  }
  __syncthreads();
  bf16* dst = vt + ((long)bh*ND + dh*64)*NT + tt*64;
#pragma unroll
  for (int i = 0; i < 2; ++i) {
    int slot = i*256 + tid, row = slot >> 3, c8 = slot & 7;
    bf16x8 v = *(const bf16x8*)(&t[row][c8*8]);
    *(bf16x8*)(dst + (long)row*NT + c8*8) = v;
  }
}

// ---------------- GEMM: C[M,N] = A[M,K] * B, with BT = B^T [N,K] row-major ----------------
template <typename OT>
__global__ __launch_bounds__(256, 2) void gemm_bt_k(const bf16* __restrict__ A, const bf16* __restrict__ BT,
                                                    OT* __restrict__ Cout, int M, int N, int K) {
  const int tid = threadIdx.x, w = tid >> 6, l = tid & 63, g = l >> 4, r = l & 15;
  const int wr = w >> 1, wc = w & 1;
  const long m0 = (long)blockIdx.y << 7, n0 = (long)blockIdx.x << 7;
  __shared__ __align__(16) char As[16384];
  __shared__ __align__(16) char Bs[16384];

  long aoff[4], boff[4];
  char *al_[4], *bl_[4];
#pragma unroll
  for (int i = 0; i < 4; ++i) {
    int slot = i*256 + tid, row = slot >> 3, c = slot & 7, cp = c ^ (row & 7);
    aoff[i] = (m0 + row)*(long)K + cp*8;
    boff[i] = (n0 + row)*(long)K + cp*8;
    al_[i] = As + ((i*256 + w*64) << 4);
    bl_[i] = Bs + ((i*256 + w*64) << 4);
  }

  const f32x4 z4 = {0.f, 0.f, 0.f, 0.f};
  f32x4 acc[4][4];
#pragma unroll
  for (int mc = 0; mc < 4; ++mc)
#pragma unroll
    for (int nc = 0; nc < 4; ++nc) acc[mc][nc] = z4;

  for (int k0 = 0; k0 < K; k0 += 64) {
#pragma unroll
    for (int i = 0; i < 4; ++i) {
      gload16(A + aoff[i] + k0, al_[i]);
      gload16(BT + boff[i] + k0, bl_[i]);
    }
    __syncthreads();
#pragma unroll
    for (int kk = 0; kk < 2; ++kk) {
      bf16x8 af[4], bfr[4];
#pragma unroll
      for (int mc = 0; mc < 4; ++mc) {
        int row = wr*64 + mc*16 + r;
        af[mc] = *(const bf16x8*)(As + row*128 + (((kk*4 + g) ^ (row & 7)) << 4));
      }
#pragma unroll
      for (int nc = 0; nc < 4; ++nc) {
        int row = wc*64 + nc*16 + r;
        bfr[nc] = *(const bf16x8*)(Bs + row*128 + (((kk*4 + g) ^ (row & 7)) << 4));
      }
#pragma unroll
      for (int mc = 0; mc < 4; ++mc)
#pragma unroll
        for (int nc = 0; nc < 4; ++nc)
          acc[mc][nc] = __builtin_amdgcn_mfma_f32_16x16x32_bf16(af[mc], bfr[nc], acc[mc][nc], 0, 0, 0);
    }
    __syncthreads();
  }
#pragma unroll
  for (int mc = 0; mc < 4; ++mc)
#pragma unroll
    for (int nc = 0; nc < 4; ++nc)
#pragma unroll
      for (int j = 0; j < 4; ++j) {
        long mr = m0 + wr*64 + mc*16 + 4*g + j;
        long nc_ = n0 + wc*64 + nc*16 + r;
        Cout[mr*(long)N + nc_] = (OT)acc[mc][nc][j];
      }
}

// ---------------- fused causal+masked flash attention (2-phase pipelined) ----------------
// block = (qx, h, b): 64 q-rows, 4 waves x 16 rows. Double-buffered K [64][128] and V^T [128][64].
__global__ __launch_bounds__(256, 2) void attn_k(const bf16* __restrict__ qkv, const bf16* __restrict__ vt,
                                                 const int* __restrict__ mask, bf16* __restrict__ y) {
  const int qx = blockIdx.x, h = blockIdx.y, b = blockIdx.z;
  const int qt = (qx & 1) ? (31 - (qx >> 1)) : (qx >> 1);   // work-balance remap (bijective)
  const int tid = threadIdx.x, w = tid >> 6, l = tid & 63, g = l >> 4, r = l & 15;
  const int q0 = qt << 6;
  const int bh = b*NH + h;

  __shared__ __align__(16) char Klds[2][16384];   // [64 key][128 d], XOR-swizzled 16B slots
  __shared__ __align__(16) char Vlds[2][16384];   // [128 d][64 key], XOR-swizzled
  __shared__ __align__(16) char Plds[8192];       // per-wave [16 q][64 key] bf16, SWZP-swizzled
  __shared__ int Mlds[2048];                      // key mask for this (b): keys 0..q0+63
  char* Pl = Plds + (w << 11);

  // cooperative mask preload (consumed after prologue barrier)
  for (int i = tid; i < q0 + 64; i += 256) Mlds[i] = mask[b*NT + i];

  long koff[4], voff[4];
  int klo[4], vlo[4];
#pragma unroll
  for (int i = 0; i < 4; ++i) {
    int slot = i*256 + tid;                       // K: 64 rows x 16 slots
    int row = slot >> 4, c = slot & 15, cp = c ^ (row & 7);
    koff[i] = (long)row*NC3 + cp*8;
    klo[i] = (i*256 + w*64) << 4;
    int vrow = slot >> 3, vc = slot & 7, vcp = vc ^ (vrow & 7);   // VT: 128 rows x 8 slots
    voff[i] = (long)vrow*NT + vcp*8;
    vlo[i] = klo[i];
  }
  const bf16* kbase0 = qkv + (long)(b*NT)*NC3 + (NC + h*ND);
  const bf16* vbase0 = vt + (long)bh*ND*NT;

  bf16x8 qf[4];
  {
    const int qrow = q0 + w*16 + r;
    const bf16* qp = qkv + (long)(b*NT + qrow)*NC3 + h*ND + g*8;
#pragma unroll
    for (int dk = 0; dk < 4; ++dk) qf[dk] = *(const bf16x8*)(qp + dk*32);
  }

  const f32x4 z4 = {0.f, 0.f, 0.f, 0.f};
  f32x4 acc[8];
#pragma unroll
  for (int i = 0; i < 8; ++i) acc[i] = z4;
  float m_run[4], l_run[4];
#pragma unroll
  for (int j = 0; j < 4; ++j) { m_run[j] = -3.0e38f; l_run[j] = 0.f; }

  const float SCL = 0.08838834764831845f * 1.4426950408889634f;  // 1/sqrt(128) * log2(e)

  // prologue: stage tile 0 into buffer 0
#pragma unroll
  for (int i = 0; i < 4; ++i) {
    gload16(kbase0 + koff[i], Klds[0] + klo[i]);
    gload16(vbase0 + voff[i], Vlds[0] + vlo[i]);
  }
  __syncthreads();

  for (int kt = 0; kt <= qt; ++kt) {
    const int cur = kt & 1;
    if (kt < qt) {                                 // stage next tile into other buffer
      const bf16* kb = kbase0 + (long)((kt+1)*64)*NC3;
      const bf16* vb = vbase0 + (kt+1)*64;
#pragma unroll
      for (int i = 0; i < 4; ++i) {
        gload16(kb + koff[i], Klds[cur^1] + klo[i]);
        gload16(vb + voff[i], Vlds[cur^1] + vlo[i]);
      }
    }
    const char* Kl = Klds[cur];
    const char* Vl = Vlds[cur];

    int mv[4];
#pragma unroll
    for (int kc = 0; kc < 4; ++kc) mv[kc] = Mlds[kt*64 + kc*16 + r];
    const int diag = (kt == qt);

    float tv[4][4];
    float tmax[4] = {-3.0e38f, -3.0e38f, -3.0e38f, -3.0e38f};
    __builtin_amdgcn_s_setprio(1);
#pragma unroll
    for (int kc = 0; kc < 4; ++kc) {
      f32x4 s = z4;
      const int krow = kc*16 + r;
#pragma unroll
      for (int dk = 0; dk < 4; ++dk) {
        bf16x8 kf = *(const bf16x8*)(Kl + krow*256 + (((dk*4 + g) ^ (krow & 7)) << 4));
        s = __builtin_amdgcn_mfma_f32_16x16x32_bf16(qf[dk], kf, s, 0, 0, 0);
      }
      const int key = kt*64 + kc*16 + r;
#pragma unroll
      for (int j = 0; j < 4; ++j) {
        int qrow = q0 + w*16 + 4*g + j;
        float sv = (mv[kc] && (!diag || key <= qrow)) ? s[j]*SCL : -3.0e38f;
        tv[kc][j] = sv;
        tmax[j] = fmaxf(tmax[j], sv);
      }
    }
    __builtin_amdgcn_s_setprio(0);
#pragma unroll
    for (int j = 0; j < 4; ++j) {
#pragma unroll
      for (int off = 1; off < 16; off <<= 1) tmax[j] = fmaxf(tmax[j], __shfl_xor(tmax[j], off));
    }
    float al[4], rs[4];
#pragma unroll
    for (int j = 0; j < 4; ++j) {
      float mn = fmaxf(m_run[j], tmax[j]);
      al[j] = exp2f(m_run[j] - mn);
      m_run[j] = mn;
      rs[j] = 0.f;
    }
#pragma unroll
    for (int kc = 0; kc < 4; ++kc) {
#pragma unroll
      for (int j = 0; j < 4; ++j) {
        float p = exp2f(tv[kc][j] - m_run[j]);
        rs[j] += p;
        int prow = 4*g + j;
        int cb = (kc*16 + r)*2;
        int sl = (cb >> 4) ^ SWZP(prow);
        *(u16*)(Pl + prow*128 + (sl << 4) + (cb & 15)) = __builtin_bit_cast(u16, (bf16)p);
      }
    }
#pragma unroll
    for (int j = 0; j < 4; ++j) {
#pragma unroll
      for (int off = 1; off < 16; off <<= 1) rs[j] += __shfl_xor(rs[j], off);
      l_run[j] = l_run[j]*al[j] + rs[j];
    }
#pragma unroll
    for (int d0 = 0; d0 < 8; ++d0) {
#pragma unroll
      for (int j = 0; j < 4; ++j) acc[d0][j] *= al[j];
    }
    // same-wave P write->read fence (rule #18)
    asm volatile("s_waitcnt lgkmcnt(0)" ::: "memory");
    __builtin_amdgcn_sched_barrier(0);
    bf16x8 pa[2];
#pragma unroll
    for (int kk = 0; kk < 2; ++kk)
      pa[kk] = *(const bf16x8*)(Pl + r*128 + (((kk*4 + g) ^ SWZP(r)) << 4));
    __builtin_amdgcn_s_setprio(1);
#pragma unroll
    for (int d0 = 0; d0 < 8; ++d0) {
      const int vrow = d0*16 + r;
#pragma unroll
      for (int kk = 0; kk < 2; ++kk) {
        bf16x8 vf = *(const bf16x8*)(Vl + vrow*128 + (((kk*4 + g) ^ (vrow & 7)) << 4));
        acc[d0] = __builtin_amdgcn_mfma_f32_16x16x32_bf16(pa[kk], vf, acc[d0], 0, 0, 0);
      }
    }
    __builtin_amdgcn_s_setprio(0);
    __syncthreads();   // drains next-tile stage (vmcnt) + guards buffer reuse
  }

  float inv[4];
#pragma unroll
  for (int j = 0; j < 4; ++j) inv[j] = 1.0f / l_run[j];
#pragma unroll
  for (int d0 = 0; d0 < 8; ++d0) {
#pragma unroll
    for (int j = 0; j < 4; ++j) {
      int qrow = q0 + w*16 + 4*g + j;
      y[(long)(b*NT + qrow)*NC + h*ND + d0*16 + r] = (bf16)(acc[d0][j]*inv[j]);
    }
  }
}

extern "C" void kernel_launch(void* const* d_in, const int* in_sizes, int n_in,
                              void* d_out, int out_size, void* d_ws, size_t ws_size,
                              hipStream_t stream) {
  const float* xr     = (const float*)d_in[0];   // inputs are f32 on device (round-4/5 evidence)
  const void*  tok    = d_in[1];
  const float* wqkvr  = (const float*)d_in[2];
  const float* wprojr = (const float*)d_in[3];
  float* out = (float*)d_out;                    // output buffer is f32
  char* ws = (char*)d_ws;

  bf16* qkv    = (bf16*)(ws);                       // 100,663,296 B
  bf16* yattn  = (bf16*)(ws + 100663296L);          //  33,554,432 B
  bf16* wT     = (bf16*)(ws + 134217728L);          //  25,165,824 B (transposed W, reused)
  bf16* wb     = (bf16*)(ws + 159383552L);          //  25,165,824 B (bf16 ingest of W, reused)
  bf16* xb     = (bf16*)(ws + 184549376L);          //  33,554,432 B (bf16 x; reused as vtb)
  bf16* vtb    = xb;                                //  alias: xb dead after GEMM1
  int*  maskI  = (int*)(ws + 218103808L);           //      32,768 B

  mask_prep_k<<<1, 256, 0, stream>>>(tok, maskI);
  // ingest x and W_qkv to bf16
  ingest_k<<<8192, 256, 0, stream>>>(xr, xb, 16777216L);
  ingest_k<<<6144, 256, 0, stream>>>(wqkvr, wb, 12582912L);
  // W_qkv^T [6144][2048]
  transpose_k<<<dim3(96, 32), 256, 0, stream>>>(wb, wT, NC3, NC);
  // qkv = x @ W_qkv
  gemm_bt_k<bf16><<<dim3(48, 64), 256, 0, stream>>>(xb, wT, qkv, 8192, 6144, 2048);
  // V^T per (b,h)  (vtb aliases xb — xb dead after GEMM1)
  vtrans_k<<<dim3(32, 2, 64), 256, 0, stream>>>(qkv, vtb);
  // W_proj ingest + transpose (reuses wb/wT)
  ingest_k<<<2048, 256, 0, stream>>>(wprojr, wb, 4194304L);
  transpose_k<<<dim3(32, 32), 256, 0, stream>>>(wb, wT, NC, NC);
  // attention
  attn_k<<<dim3(32, 16, 4), 256, 0, stream>>>(qkv, vtb, maskI, yattn);
  // out = y @ W_proj  (f32 output)
  gemm_bt_k<float><<<dim3(16, 64), 256, 0, stream>>>(yattn, wT, out, 8192, 2048, 2048);
}

// Round 7
// 641.619 us; speedup vs baseline: 1.0808x; 1.0329x over previous
//
#include <hip/hip_runtime.h>
#include <hip/hip_bf16.h>
#include <stdint.h>

typedef __bf16 bf16;
typedef __bf16 bf16x8 __attribute__((ext_vector_type(8)));
typedef float f32x4 __attribute__((ext_vector_type(4)));
typedef unsigned short u16;

constexpr int NB = 4;
constexpr int NT = 2048;
constexpr int NC = 2048;
constexpr int NH = 16;
constexpr int ND = 128;
constexpr int NC3 = 6144;

#define SWZP(row) ((((row) >> 2) << 1) | ((row) & 1))

__device__ __forceinline__ void gload16(const void* g, void* l) {
  __builtin_amdgcn_global_load_lds((const __attribute__((address_space(1))) void*)g,
                                   (__attribute__((address_space(3))) void*)l, 16, 0, 0);
}

// ---------------- ingest: f32 -> bf16, n multiple of 8 ----------------
__global__ __launch_bounds__(256) void ingest_k(const float* __restrict__ raw, bf16* __restrict__ out, long n) {
  long i = ((long)blockIdx.x * 256 + threadIdx.x) * 8;
  if (i >= n) return;
  f32x4 a = *(const f32x4*)(raw + i), b = *(const f32x4*)(raw + i + 4);
  bf16x8 o;
  o[0] = (bf16)a[0]; o[1] = (bf16)a[1]; o[2] = (bf16)a[2]; o[3] = (bf16)a[3];
  o[4] = (bf16)b[0]; o[5] = (bf16)b[1]; o[6] = (bf16)b[2]; o[7] = (bf16)b[3];
  *(bf16x8*)(out + i) = o;
}

// ---------------- mask format detect + expand to int32 (proven) ----------------
__global__ void mask_prep_k(const void* raw, int* out) {
  __shared__ int s_gt1, s_oddnz, s_allb, s_allf, s_allh;
  if (threadIdx.x == 0) { s_gt1 = 0; s_oddnz = 0; s_allb = 1; s_allf = 1; s_allh = 1; }
  __syncthreads();
  const unsigned int* mw = (const unsigned int*)raw;
  int gt1 = 0, oddnz = 0, allb = 1, allf = 1, allh = 1;
  for (int i = threadIdx.x; i < 2048; i += 256) {
    unsigned v = mw[i];
    if (v > 1u) gt1 = 1;
    if ((i & 1) && v) oddnz = 1;
#pragma unroll
    for (int bb = 0; bb < 4; ++bb) { unsigned by = (v >> (8*bb)) & 0xffu; if (by > 1u) allb = 0; }
    if (v != 0u && v != 0x3F800000u) allf = 0;
    unsigned lo = v & 0xffffu, hi = v >> 16;
    if ((lo != 0u && lo != 0x3F80u) || (hi != 0u && hi != 0x3F80u)) allh = 0;
  }
  if (gt1) atomicOr(&s_gt1, 1);
  if (oddnz) atomicOr(&s_oddnz, 1);
  if (!allb) atomicAnd(&s_allb, 0);
  if (!allf) atomicAnd(&s_allf, 0);
  if (!allh) atomicAnd(&s_allh, 0);
  __syncthreads();
  int mode;
  if (!s_gt1)       mode = s_oddnz ? 0 : 2;
  else if (s_allf)  mode = 3;
  else if (s_allb)  mode = 1;
  else if (s_allh)  mode = 4;
  else              mode = 0;
  for (int i = threadIdx.x; i < NB*NT; i += 256) {
    int v;
    if (mode == 0)      v = (((const int*)raw)[i] != 0);
    else if (mode == 1) v = (((const unsigned char*)raw)[i] != 0);
    else if (mode == 2) v = (((const long long*)raw)[i] != 0);
    else if (mode == 3) v = (((const unsigned int*)raw)[i] != 0);
    else                v = (((const unsigned short*)raw)[i] != 0);
    out[i] = v;
  }
}

// ---------------- fused transpose+cast: out[c][r] = bf16(in_f32[r][c]), 64x64 tiles ----------------
__global__ __launch_bounds__(256) void transpose_f32_k(const float* __restrict__ in, bf16* __restrict__ out,
                                                       int in_rs, int out_rs) {
  __shared__ __align__(16) bf16 t[64][72];
  const int r0 = blockIdx.y << 6, c0 = blockIdx.x << 6;
  const int tid = threadIdx.x;
#pragma unroll
  for (int i = 0; i < 4; ++i) {
    int slot = i*256 + tid, row = slot >> 4, c4 = slot & 15;
    f32x4 v = *(const f32x4*)(in + (long)(r0 + row)*in_rs + c0 + c4*4);
#pragma unroll
    for (int e = 0; e < 4; ++e) t[c4*4 + e][row] = (bf16)v[e];
  }
  __syncthreads();
#pragma unroll
  for (int i = 0; i < 2; ++i) {
    int slot = i*256 + tid, row = slot >> 3, c8 = slot & 7;
    bf16x8 v = *(const bf16x8*)(&t[row][c8*8]);
    *(bf16x8*)(out + (long)(c0 + row)*out_rs + r0 + c8*8) = v;
  }
}

// ---------------- V^T extraction: vt[(b*H+h)*128 + d][t] = qkv[b*T+t][4096 + h*128 + d] ----------------
__global__ __launch_bounds__(256) void vtrans_k(const bf16* __restrict__ qkv, bf16* __restrict__ vt) {
  __shared__ __align__(16) bf16 t[64][72];
  const int tt = blockIdx.x, dh = blockIdx.y, bh = blockIdx.z;
  const int b = bh >> 4, h = bh & 15;
  const int tid = threadIdx.x;
  const bf16* src = qkv + (long)(b*NT + tt*64)*NC3 + (2*NC + h*ND + dh*64);
#pragma unroll
  for (int i = 0; i < 2; ++i) {
    int slot = i*256 + tid, row = slot >> 3, c8 = slot & 7;
    bf16x8 v = *(const bf16x8*)(src + (long)row*NC3 + c8*8);
#pragma unroll
    for (int e = 0; e < 8; ++e) t[c8*8 + e][row] = v[e];
  }
  __syncthreads();
  bf16* dst = vt + ((long)bh*ND + dh*64)*NT + tt*64;
#pragma unroll
  for (int i = 0; i < 2; ++i) {
    int slot = i*256 + tid, row = slot >> 3, c8 = slot & 7;
    bf16x8 v = *(const bf16x8*)(&t[row][c8*8]);
    *(bf16x8*)(dst + (long)row*NT + c8*8) = v;
  }
}

// ---------------- GEMM: C[M,N] = A[M,K] * B, with BT = B^T [N,K] row-major ----------------
template <typename OT>
__global__ __launch_bounds__(256, 2) void gemm_bt_k(const bf16* __restrict__ A, const bf16* __restrict__ BT,
                                                    OT* __restrict__ Cout, int M, int N, int K) {
  const int tid = threadIdx.x, w = tid >> 6, l = tid & 63, g = l >> 4, r = l & 15;
  const int wr = w >> 1, wc = w & 1;
  const long m0 = (long)blockIdx.y << 7, n0 = (long)blockIdx.x << 7;
  __shared__ __align__(16) char As[16384];
  __shared__ __align__(16) char Bs[16384];

  long aoff[4], boff[4];
  char *al_[4], *bl_[4];
#pragma unroll
  for (int i = 0; i < 4; ++i) {
    int slot = i*256 + tid, row = slot >> 3, c = slot & 7, cp = c ^ (row & 7);
    aoff[i] = (m0 + row)*(long)K + cp*8;
    boff[i] = (n0 + row)*(long)K + cp*8;
    al_[i] = As + ((i*256 + w*64) << 4);
    bl_[i] = Bs + ((i*256 + w*64) << 4);
  }

  const f32x4 z4 = {0.f, 0.f, 0.f, 0.f};
  f32x4 acc[4][4];
#pragma unroll
  for (int mc = 0; mc < 4; ++mc)
#pragma unroll
    for (int nc = 0; nc < 4; ++nc) acc[mc][nc] = z4;

  for (int k0 = 0; k0 < K; k0 += 64) {
#pragma unroll
    for (int i = 0; i < 4; ++i) {
      gload16(A + aoff[i] + k0, al_[i]);
      gload16(BT + boff[i] + k0, bl_[i]);
    }
    __syncthreads();
#pragma unroll
    for (int kk = 0; kk < 2; ++kk) {
      bf16x8 af[4], bfr[4];
#pragma unroll
      for (int mc = 0; mc < 4; ++mc) {
        int row = wr*64 + mc*16 + r;
        af[mc] = *(const bf16x8*)(As + row*128 + (((kk*4 + g) ^ (row & 7)) << 4));
      }
#pragma unroll
      for (int nc = 0; nc < 4; ++nc) {
        int row = wc*64 + nc*16 + r;
        bfr[nc] = *(const bf16x8*)(Bs + row*128 + (((kk*4 + g) ^ (row & 7)) << 4));
      }
#pragma unroll
      for (int mc = 0; mc < 4; ++mc)
#pragma unroll
        for (int nc = 0; nc < 4; ++nc)
          acc[mc][nc] = __builtin_amdgcn_mfma_f32_16x16x32_bf16(af[mc], bfr[nc], acc[mc][nc], 0, 0, 0);
    }
    __syncthreads();
  }
#pragma unroll
  for (int mc = 0; mc < 4; ++mc)
#pragma unroll
    for (int nc = 0; nc < 4; ++nc)
#pragma unroll
      for (int j = 0; j < 4; ++j) {
        long mr = m0 + wr*64 + mc*16 + 4*g + j;
        long nc_ = n0 + wc*64 + nc*16 + r;
        Cout[mr*(long)N + nc_] = (OT)acc[mc][nc][j];
      }
}

// ---------------- fused causal+masked flash attention, QBLK=128 ----------------
// block = (qx,h,b): 128 q-rows, 4 waves x 32 rows (2 chunks of 16). KVBLK=64, K/V double-buffered.
// LDS = 74KB -> 2 blocks/CU. K-frags shared across chunks; V-frags shared in fused PV.
__global__ __launch_bounds__(256, 2) void attn_k(const bf16* __restrict__ qkv, const bf16* __restrict__ vt,
                                                 const int* __restrict__ mask, bf16* __restrict__ y) {
  const int qx = blockIdx.x, h = blockIdx.y, b = blockIdx.z;
  const int qb = (qx & 1) ? (15 - (qx >> 1)) : (qx >> 1);   // work-balance remap (bijective)
  const int tid = threadIdx.x, w = tid >> 6, l = tid & 63, g = l >> 4, r = l & 15;
  const int q0 = qb << 7;
  const int bh = b*NH + h;
  const int ntiles = (q0 + 128) >> 6;                        // 2qb+2

  __shared__ __align__(16) char Klds[2][16384];   // [64 key][128 d], swizzled 16B slots
  __shared__ __align__(16) char Vlds[2][16384];   // [128 d][64 key], swizzled
  __shared__ __align__(16) char Plds[8192];       // per-wave [16 q][64 key] bf16 (reused per chunk)
  __shared__ char Mc[2048];                       // key mask (char) for this b
  char* Pl = Plds + (w << 11);

  for (int i = tid; i < q0 + 128; i += 256) Mc[i] = (char)(mask[b*NT + i] != 0);

  long koff[4], voff[4];
  int klo[4];
#pragma unroll
  for (int i = 0; i < 4; ++i) {
    int slot = i*256 + tid;                       // K: 64 rows x 16 slots
    int row = slot >> 4, c = slot & 15, cp = c ^ (row & 7);
    koff[i] = (long)row*NC3 + cp*8;
    klo[i] = (i*256 + w*64) << 4;
    int vrow = slot >> 3, vc = slot & 7, vcp = vc ^ (vrow & 7);   // VT: 128 rows x 8 slots
    voff[i] = (long)vrow*NT + vcp*8;
  }
  const bf16* kbase0 = qkv + (long)(b*NT)*NC3 + (NC + h*ND);
  const bf16* vbase0 = vt + (long)bh*ND*NT;

  bf16x8 qf[2][4];
#pragma unroll
  for (int jj = 0; jj < 2; ++jj) {
    const int qrow = q0 + w*32 + jj*16 + r;
    const bf16* qp = qkv + (long)(b*NT + qrow)*NC3 + h*ND + g*8;
#pragma unroll
    for (int dk = 0; dk < 4; ++dk) qf[jj][dk] = *(const bf16x8*)(qp + dk*32);
  }

  const f32x4 z4 = {0.f, 0.f, 0.f, 0.f};
  f32x4 acc[2][8];
#pragma unroll
  for (int jj = 0; jj < 2; ++jj)
#pragma unroll
    for (int i = 0; i < 8; ++i) acc[jj][i] = z4;
  float m_run[2][4], l_run[2][4];
#pragma unroll
  for (int jj = 0; jj < 2; ++jj)
#pragma unroll
    for (int j = 0; j < 4; ++j) { m_run[jj][j] = -3.0e38f; l_run[jj][j] = 0.f; }

  const float SCL = 0.08838834764831845f * 1.4426950408889634f;  // 1/sqrt(128) * log2(e)

  // prologue: stage tile 0 into buffer 0
#pragma unroll
  for (int i = 0; i < 4; ++i) {
    gload16(kbase0 + koff[i], Klds[0] + klo[i]);
    gload16(vbase0 + voff[i], Vlds[0] + klo[i]);
  }
  __syncthreads();

  for (int kt = 0; kt < ntiles; ++kt) {
    const int cur = kt & 1;
    if (kt + 1 < ntiles) {
      const bf16* kb = kbase0 + (long)((kt+1)*64)*NC3;
      const bf16* vb = vbase0 + (kt+1)*64;
#pragma unroll
      for (int i = 0; i < 4; ++i) {
        gload16(kb + koff[i], Klds[cur^1] + klo[i]);
        gload16(vb + voff[i], Vlds[cur^1] + klo[i]);
      }
    }
    const char* Kl = Klds[cur];
    const char* Vl = Vlds[cur];
    const int key0 = kt*64;
    // chunk-active flags (wave-uniform): chunk fully masked once key0 exceeds its max row
    const bool act1 = (key0 <= q0 + w*32 + 31);
    const bool act0 = (key0 <= q0 + w*32 + 15);

    char mvc[4];
#pragma unroll
    for (int kc = 0; kc < 4; ++kc) mvc[kc] = Mc[key0 + kc*16 + r];

    float tv[2][4][4];
    if (act1) {
      __builtin_amdgcn_s_setprio(1);
#pragma unroll
      for (int kc = 0; kc < 4; ++kc) {
        const int krow = kc*16 + r;
        bf16x8 kf[4];
#pragma unroll
        for (int dk = 0; dk < 4; ++dk)
          kf[dk] = *(const bf16x8*)(Kl + krow*256 + (((dk*4 + g) ^ (krow & 7)) << 4));
        f32x4 s0 = z4, s1 = z4;
#pragma unroll
        for (int dk = 0; dk < 4; ++dk) {
          s0 = __builtin_amdgcn_mfma_f32_16x16x32_bf16(qf[0][dk], kf[dk], s0, 0, 0, 0);
          s1 = __builtin_amdgcn_mfma_f32_16x16x32_bf16(qf[1][dk], kf[dk], s1, 0, 0, 0);
        }
        const int key = key0 + krow;
#pragma unroll
        for (int j = 0; j < 4; ++j) {
          const int qr0 = q0 + w*32 + 4*g + j;          // chunk0 row; chunk1 row = qr0+16
          tv[0][kc][j] = (mvc[kc] && key <= qr0)      ? s0[j]*SCL : -3.0e38f;
          tv[1][kc][j] = (mvc[kc] && key <= qr0 + 16) ? s1[j]*SCL : -3.0e38f;
        }
      }
      __builtin_amdgcn_s_setprio(0);
    }

    bf16x8 pa0[2], pa1[2];
#pragma unroll
    for (int jj = 0; jj < 2; ++jj) {
      const bool act = jj ? act1 : act0;
      if (act) {
        float tmax[4] = {-3.0e38f, -3.0e38f, -3.0e38f, -3.0e38f};
#pragma unroll
        for (int kc = 0; kc < 4; ++kc)
#pragma unroll
          for (int j = 0; j < 4; ++j) tmax[j] = fmaxf(tmax[j], tv[jj][kc][j]);
#pragma unroll
        for (int j = 0; j < 4; ++j) {
#pragma unroll
          for (int off = 1; off < 16; off <<= 1) tmax[j] = fmaxf(tmax[j], __shfl_xor(tmax[j], off));
        }
        float al[4], rs[4];
#pragma unroll
        for (int j = 0; j < 4; ++j) {
          float mn = fmaxf(m_run[jj][j], tmax[j]);
          al[j] = exp2f(m_run[jj][j] - mn);
          m_run[jj][j] = mn;
          rs[j] = 0.f;
        }
#pragma unroll
        for (int kc = 0; kc < 4; ++kc) {
#pragma unroll
          for (int j = 0; j < 4; ++j) {
            float p = exp2f(tv[jj][kc][j] - m_run[jj][j]);
            rs[j] += p;
            int prow = 4*g + j;
            int cb = (kc*16 + r)*2;
            int sl = (cb >> 4) ^ SWZP(prow);
            *(u16*)(Pl + prow*128 + (sl << 4) + (cb & 15)) = __builtin_bit_cast(u16, (bf16)p);
          }
        }
#pragma unroll
        for (int j = 0; j < 4; ++j) {
#pragma unroll
          for (int off = 1; off < 16; off <<= 1) rs[j] += __shfl_xor(rs[j], off);
          l_run[jj][j] = l_run[jj][j]*al[j] + rs[j];
        }
#pragma unroll
        for (int d0 = 0; d0 < 8; ++d0)
#pragma unroll
          for (int j = 0; j < 4; ++j) acc[jj][d0][j] *= al[j];
        // P write -> read fence (same-wave DS in-order; pin compiler too)
        asm volatile("s_waitcnt lgkmcnt(0)" ::: "memory");
        __builtin_amdgcn_sched_barrier(0);
#pragma unroll
        for (int kk = 0; kk < 2; ++kk) {
          bf16x8 pv = *(const bf16x8*)(Pl + r*128 + (((kk*4 + g) ^ SWZP(r)) << 4));
          if (jj) pa1[kk] = pv; else pa0[kk] = pv;
        }
        asm volatile("s_waitcnt lgkmcnt(0)" ::: "memory");   // pa in regs before P reuse by next chunk
        __builtin_amdgcn_sched_barrier(0);
      }
    }

    if (act1) {
      __builtin_amdgcn_s_setprio(1);
#pragma unroll
      for (int d0 = 0; d0 < 8; ++d0) {
        const int vrow = d0*16 + r;
#pragma unroll
        for (int kk = 0; kk < 2; ++kk) {
          bf16x8 vf = *(const bf16x8*)(Vl + vrow*128 + (((kk*4 + g) ^ (vrow & 7)) << 4));
          if (act0) acc[0][d0] = __builtin_amdgcn_mfma_f32_16x16x32_bf16(pa0[kk], vf, acc[0][d0], 0, 0, 0);
          acc[1][d0] = __builtin_amdgcn_mfma_f32_16x16x32_bf16(pa1[kk], vf, acc[1][d0], 0, 0, 0);
        }
      }
      __builtin_amdgcn_s_setprio(0);
    }
    __syncthreads();   // next-tile stage complete + guards buffer reuse
  }

#pragma unroll
  for (int jj = 0; jj < 2; ++jj) {
    float inv[4];
#pragma unroll
    for (int j = 0; j < 4; ++j) inv[j] = 1.0f / l_run[jj][j];
#pragma unroll
    for (int d0 = 0; d0 < 8; ++d0)
#pragma unroll
      for (int j = 0; j < 4; ++j) {
        int qrow = q0 + w*32 + jj*16 + 4*g + j;
        y[(long)(b*NT + qrow)*NC + h*ND + d0*16 + r] = (bf16)(acc[jj][d0][j]*inv[j]);
      }
  }
}

extern "C" void kernel_launch(void* const* d_in, const int* in_sizes, int n_in,
                              void* d_out, int out_size, void* d_ws, size_t ws_size,
                              hipStream_t stream) {
  const float* xr     = (const float*)d_in[0];   // f32 inputs (round-6 proven)
  const void*  tok    = d_in[1];
  const float* wqkvr  = (const float*)d_in[2];
  const float* wprojr = (const float*)d_in[3];
  float* out = (float*)d_out;                    // f32 output
  char* ws = (char*)d_ws;

  bf16* qkv    = (bf16*)(ws);                       // 100,663,296 B
  bf16* yattn  = (bf16*)(ws + 100663296L);          //  33,554,432 B
  bf16* wT     = (bf16*)(ws + 134217728L);          //  25,165,824 B  W_qkv^T
  bf16* wpT    = (bf16*)(ws + 159383552L);          //   8,388,608 B  W_proj^T
  bf16* xb     = (bf16*)(ws + 167772160L);          //  33,554,432 B  bf16 x; reused as vtb
  bf16* vtb    = xb;                                //  alias: xb dead after GEMM1
  int*  maskI  = (int*)(ws + 201326592L);           //      32,768 B

  mask_prep_k<<<1, 256, 0, stream>>>(tok, maskI);
  ingest_k<<<8192, 256, 0, stream>>>(xr, xb, 16777216L);
  // fused cast+transpose of weights (f32 -> bf16, transposed)
  transpose_f32_k<<<dim3(96, 32), 256, 0, stream>>>(wqkvr, wT, NC3, NC);
  transpose_f32_k<<<dim3(32, 32), 256, 0, stream>>>(wprojr, wpT, NC, NC);
  // qkv = x @ W_qkv
  gemm_bt_k<bf16><<<dim3(48, 64), 256, 0, stream>>>(xb, wT, qkv, 8192, 6144, 2048);
  // V^T per (b,h)  (vtb aliases xb — xb dead after GEMM1)
  vtrans_k<<<dim3(32, 2, 64), 256, 0, stream>>>(qkv, vtb);
  // attention (QBLK=128)
  attn_k<<<dim3(16, 16, 4), 256, 0, stream>>>(qkv, vtb, maskI, yattn);
  // out = y @ W_proj  (f32 output)
  gemm_bt_k<float><<<dim3(16, 64), 256, 0, stream>>>(yattn, wpT, out, 8192, 2048, 2048);
}